// Round 8
// baseline (117.618 us; speedup 1.0000x reference)
//
#include <hip/hip_runtime.h>

#define D 128

typedef __attribute__((ext_vector_type(8))) short short8;   // 8 bf16 (4 VGPRs)
typedef __attribute__((ext_vector_type(4))) float floatx4;  // MFMA acc

__device__ __forceinline__ float bf_lo(unsigned u) { return __uint_as_float(u << 16); }
__device__ __forceinline__ float bf_hi(unsigned u) { return __uint_as_float(u & 0xffff0000u); }
__device__ __forceinline__ unsigned pack_bf16(float a, float b) {
    unsigned ua = __float_as_uint(a), ub = __float_as_uint(b);
    ua = (ua + 0x7fffu + ((ua >> 16) & 1u)) >> 16;   // RNE
    ub = (ub + 0x7fffu + ((ub >> 16) & 1u)) >> 16;
    return ua | (ub << 16);
}

// ---------------------------------------------------------------------------
// Fused prep: [A] features f32->bf16 | [B] packed (ij,w) u64 records + seg
// offsets | [C] W -> Wt bf16 transposed ([col][k-pairs]).
// ---------------------------------------------------------------------------
__global__ __launch_bounds__(256) void prep_kernel(
    const float* __restrict__ F, const float* __restrict__ pw,
    const float* __restrict__ W, const int* __restrict__ pi,
    const int* __restrict__ pj, const int* __restrict__ nidx,
    unsigned* __restrict__ Fb, unsigned long long* __restrict__ rec,
    int* __restrict__ offs, unsigned* __restrict__ Wt,
    int n_nodes, int n_pairs) {
    const int B1 = (n_nodes * (D / 4) + 255) / 256;
    const int B2 = (n_pairs + 255) / 256;
    const int b = blockIdx.x;
    if (b < B1) {                       // features -> bf16
        int t = b * 256 + threadIdx.x;
        if (t >= n_nodes * (D / 4)) return;
        float4 v = reinterpret_cast<const float4*>(F)[t];
        uint2 o = {pack_bf16(v.x, v.y), pack_bf16(v.z, v.w)};
        reinterpret_cast<uint2*>(Fb)[t] = o;
    } else if (b < B1 + B2) {           // records + offsets
        int p = (b - B1) * 256 + threadIdx.x;
        if (p >= n_pairs) return;
        unsigned ijv = (unsigned)pi[p] | ((unsigned)pj[p] << 16);
        rec[p] = (unsigned long long)ijv |
                 ((unsigned long long)__float_as_uint(pw[p]) << 32);
        int cur  = nidx[p];
        int prev = p ? nidx[p - 1] : -1;
        for (int n = prev + 1; n <= cur; ++n) offs[n] = p;
        if (p == n_pairs - 1)
            for (int n = cur + 1; n <= n_nodes; ++n) offs[n] = n_pairs;
    } else {                            // Wt[c][kk] = pack(W[2kk][c], W[2kk+1][c])
        int t = (b - B1 - B2) * 256 + threadIdx.x;
        if (t >= D * (D / 2)) return;
        int c = t >> 6, kk = t & 63;
        Wt[t] = pack_bf16(W[(2 * kk) * D + c], W[(2 * kk + 1) * D + c]);
    }
}

// ---------------------------------------------------------------------------
// Aggregate: wave per (node, half-row cg); cg = blockIdx&1 -> XCD-pinned
// slice (validated R3/R5/R6). Wave = 8 groups x 8 lanes; lane gathers
// uint4 = 16 B (8 bf16 cols). MLP fix (R6 post-mortem: Little's-law bound):
// fixed-trip-count unrolled chunks issue 8 gathers back-to-back instead of
// one dependent pair per step. Group g loads its own 8B u64 record.
// ---------------------------------------------------------------------------
#define PAIR_BODY(r)                                                          \
    {                                                                         \
        const unsigned ij_ = (unsigned)(r);                                   \
        const unsigned i_  = ij_ & 0xffffu;                                   \
        const unsigned j_  = ij_ >> 16;                                       \
        const float    w_  = __uint_as_float((unsigned)((r) >> 32));          \
        const uint4 ui = *reinterpret_cast<const uint4*>(base + (size_t)i_ * 64); \
        const uint4 uj = *reinterpret_cast<const uint4*>(base + (size_t)j_ * 64); \
        a0 += (bf_lo(ui.x) + bf_lo(uj.x)) * w_;                               \
        a1 += (bf_hi(ui.x) + bf_hi(uj.x)) * w_;                               \
        a2 += (bf_lo(ui.y) + bf_lo(uj.y)) * w_;                               \
        a3 += (bf_hi(ui.y) + bf_hi(uj.y)) * w_;                               \
        a4 += (bf_lo(ui.z) + bf_lo(uj.z)) * w_;                               \
        a5 += (bf_hi(ui.z) + bf_hi(uj.z)) * w_;                               \
        a6 += (bf_lo(ui.w) + bf_lo(uj.w)) * w_;                               \
        a7 += (bf_hi(ui.w) + bf_hi(uj.w)) * w_;                               \
    }

__global__ __launch_bounds__(256) void aggregate_kernel(
    const unsigned* __restrict__ Fb, const unsigned long long* __restrict__ rec,
    const int* __restrict__ offs, unsigned* __restrict__ aggb, int n_nodes) {
    const int cg  = blockIdx.x & 1;
    const int wid = threadIdx.x >> 6;
    const int n   = (blockIdx.x >> 1) * 4 + wid;
    if (n >= n_nodes) return;
    const int start = offs[n];
    const int end   = offs[n + 1];
    const int lane  = threadIdx.x & 7;
    const int g     = (threadIdx.x >> 3) & 7;

    const unsigned* __restrict__ base = Fb + cg * 32 + lane * 4;  // uint units

    float a0 = 0.f, a1 = 0.f, a2 = 0.f, a3 = 0.f;
    float a4 = 0.f, a5 = 0.f, a6 = 0.f, a7 = 0.f;

    int p = start;
    // 32-pair chunks: 4 unrolled steps -> 8 gathers in flight
    for (; p + 32 <= end; p += 32) {
        unsigned long long r0 = __builtin_nontemporal_load(rec + p + 0 * 8 + g);
        unsigned long long r1 = __builtin_nontemporal_load(rec + p + 1 * 8 + g);
        unsigned long long r2 = __builtin_nontemporal_load(rec + p + 2 * 8 + g);
        unsigned long long r3 = __builtin_nontemporal_load(rec + p + 3 * 8 + g);
        PAIR_BODY(r0)
        PAIR_BODY(r1)
        PAIR_BODY(r2)
        PAIR_BODY(r3)
    }
    // one 16-pair chunk: 2 unrolled steps
    if (p + 16 <= end) {
        unsigned long long r0 = __builtin_nontemporal_load(rec + p + 0 * 8 + g);
        unsigned long long r1 = __builtin_nontemporal_load(rec + p + 1 * 8 + g);
        PAIR_BODY(r0)
        PAIR_BODY(r1)
        p += 16;
    }
    // predicated tail (< 16 pairs)
    for (int q = p + g; q < end; q += 8) {
        unsigned long long r = __builtin_nontemporal_load(rec + q);
        PAIR_BODY(r)
    }

#pragma unroll
    for (int m = 8; m <= 32; m <<= 1) {
        a0 += __shfl_xor(a0, m); a1 += __shfl_xor(a1, m);
        a2 += __shfl_xor(a2, m); a3 += __shfl_xor(a3, m);
        a4 += __shfl_xor(a4, m); a5 += __shfl_xor(a5, m);
        a6 += __shfl_xor(a6, m); a7 += __shfl_xor(a7, m);
    }

    if (g == 0) {
        uint4 o = {pack_bf16(a0, a1), pack_bf16(a2, a3),
                   pack_bf16(a4, a5), pack_bf16(a6, a7)};
        *reinterpret_cast<uint4*>(aggb + (size_t)n * 64 + cg * 32 + lane * 4) = o;
    }
}

// ---------------------------------------------------------------------------
// Proj (MFMA): out = aggb(bf16) @ W + bias, f32 acc via mfma_f32_16x16x32_bf16.
// (validated R6: absmax unchanged). Block = 4 waves x 16 rows.
// ---------------------------------------------------------------------------
__global__ __launch_bounds__(256) void proj_kernel(
    const unsigned* __restrict__ aggb, const unsigned* __restrict__ Wt,
    const float* __restrict__ bias, float* __restrict__ out, int M) {
    const int wid = threadIdx.x >> 6;
    const int l   = threadIdx.x & 63;
    const int lr  = l & 15;
    const int lk  = l >> 4;
    const int row_base = blockIdx.x * 64 + wid * 16;

    int arow = row_base + lr;
    if (arow >= M) arow = M - 1;  // clamp; stores predicated

    const short8* __restrict__ A8 = reinterpret_cast<const short8*>(aggb);
    const short8* __restrict__ B8 = reinterpret_cast<const short8*>(Wt);

    floatx4 acc[8];
#pragma unroll
    for (int t = 0; t < 8; ++t) acc[t] = (floatx4){0.f, 0.f, 0.f, 0.f};

#pragma unroll
    for (int ks = 0; ks < 4; ++ks) {
        const short8 a = A8[(size_t)arow * 16 + ks * 4 + lk];
#pragma unroll
        for (int t = 0; t < 8; ++t) {
            const short8 bfr = B8[(size_t)(t * 16 + lr) * 16 + ks * 4 + lk];
            acc[t] = __builtin_amdgcn_mfma_f32_16x16x32_bf16(a, bfr, acc[t], 0, 0, 0);
        }
    }

#pragma unroll
    for (int t = 0; t < 8; ++t) {
        const float bcol = bias[t * 16 + lr];
#pragma unroll
        for (int r = 0; r < 4; ++r) {
            const int row = row_base + lk * 4 + r;
            if (row < M)
                out[(size_t)row * D + t * 16 + lr] = acc[t][r] + bcol;
        }
    }
}

// ---------------------------------------------------------------------------
extern "C" void kernel_launch(void* const* d_in, const int* in_sizes, int n_in,
                              void* d_out, int out_size, void* d_ws, size_t ws_size,
                              hipStream_t stream) {
    const float* F    = (const float*)d_in[0];
    const float* pw   = (const float*)d_in[1];
    const float* W    = (const float*)d_in[2];
    const float* bias = (const float*)d_in[3];
    const int*   pi   = (const int*)d_in[4];
    const int*   pj   = (const int*)d_in[5];
    const int*   nidx = (const int*)d_in[6];
    float* out = (float*)d_out;

    const int n_pairs = in_sizes[1];
    const int n_nodes = in_sizes[0] / D;

    // ws layout: aggb | offs | rec | Wt | [Fb]
    const size_t aggb_bytes = (size_t)n_nodes * D * 2;
    const size_t offs_bytes = ((size_t)(n_nodes + 1) * 4 + 255) & ~(size_t)255;
    const size_t rec_bytes  = (size_t)n_pairs * 8;
    const size_t wt_bytes   = (size_t)D * (D / 2) * 4;
    const size_t fb_bytes   = (size_t)n_nodes * D * 2;

    char* pp = (char*)d_ws;
    unsigned* aggb = (unsigned*)pp;                pp += aggb_bytes;
    int*      offs = (int*)pp;                     pp += offs_bytes;
    unsigned long long* rec = (unsigned long long*)pp;  pp += rec_bytes;
    unsigned* Wt   = (unsigned*)pp;                pp += wt_bytes;
    size_t used = (size_t)(pp - (char*)d_ws);
    unsigned* Fb = (ws_size >= used + fb_bytes)
                 ? (unsigned*)pp
                 : (unsigned*)d_out;  // proj writes out last; Fb dead by then

    const int B1 = (n_nodes * (D / 4) + 255) / 256;
    const int B2 = (n_pairs + 255) / 256;
    const int B3 = (D * (D / 2) + 255) / 256;
    prep_kernel<<<B1 + B2 + B3, 256, 0, stream>>>(F, pw, W, pi, pj, nidx,
                                                  Fb, rec, offs, Wt,
                                                  n_nodes, n_pairs);
    const int nb = (n_nodes + 3) / 4;  // 4 node-waves per block
    aggregate_kernel<<<nb * 2, 256, 0, stream>>>(Fb, rec, offs, aggb, n_nodes);
    proj_kernel<<<(n_nodes + 63) / 64, 256, 0, stream>>>(aggb, Wt, bias, out, n_nodes);
}